// Round 3
// baseline (73.022 us; speedup 1.0000x reference)
//
#include <hip/hip_runtime.h>
#include <hip/hip_bf16.h>
#include <math.h>

#define NTOK   1024
#define DMODEL 256
#define NFREQ  128
#define TILE   32
#define NT     (NTOK/TILE)          // 32 tiles
#define NPAIRS (NT*(NT+1)/2)        // 528 tile-pairs
#define FOUR_PI_F 12.566370614359172f
#define INV_2PI_F 0.15915494309189535f
#define EPS_F  1e-6f
#define LN_EPS_F 1e-5f
#define SCALE_F     16777216.0f                 // 2^24 fixed-point scale
#define INV_SCALE_F 5.9604644775390625e-8f      // 2^-24

// Symmetric pair kernel: r_ij == r_ji, so each unordered tile-pair (ta,tb)
// computes trig once and accumulates BOTH out-rows-A (I-side, registers) and
// out-rows-B (J-side, per-j scalar). Deterministic integer fixed-point
// atomics into acc (d_out reinterpreted as int32).
__global__ __launch_bounds__(256) void wf_pair_kernel(
    const float* __restrict__ coords,       // [N,3]
    const float* __restrict__ wavenumbers,  // [NFREQ]
    const unsigned char* __restrict__ mask, // [N], nonzero = padded
    int* __restrict__ acc)                  // [N, DMODEL] fixed-point accum
{
    // decode blockIdx -> (ta, tb) with ta <= tb
    int b = blockIdx.x;
    int ta = 0, len = NT;
    while (b >= len) { b -= len; ta++; len--; }
    const int tb = ta + b;
    const bool diag = (ta == tb);

    const int tid  = threadIdx.x;
    const int f    = tid & (NFREQ - 1);
    const int trig = tid >> 7;                   // 0: cos(real), 1: sin(imag)
    const int feat = trig ? (NFREQ + f) : f;

    __shared__ float4 tile[TILE][TILE];  // (r*inv2pi, wI(src mask j), wJ(src mask i), 0)

    for (int p = tid; p < TILE*TILE; p += 256) {
        int i  = p >> 5, j = p & (TILE-1);
        int ig = ta*TILE + i, jg = tb*TILE + j;
        float dx = coords[ig*3+0] - coords[jg*3+0];
        float dy = coords[ig*3+1] - coords[jg*3+1];
        float dz = coords[ig*3+2] - coords[jg*3+2];
        float r  = sqrtf(dx*dx + dy*dy + dz*dz);
        float w0 = (r > EPS_F) ? (1.0f/(FOUR_PI_F*r)) : 0.0f;
        float wI = mask[jg] ? 0.0f : w0;   // weight when target in A, source j in B
        float wJ = mask[ig] ? 0.0f : w0;   // weight when target in B, source i in A
        tile[i][j] = make_float4(r * INV_2PI_F, wI, wJ, 0.0f);
    }
    __syncthreads();

    const float kf = wavenumbers[f];

    float accI[TILE];
    #pragma unroll
    for (int i = 0; i < TILE; ++i) accI[i] = 0.0f;

    for (int j = 0; j < TILE; ++j) {
        float accJ = 0.0f;
        #pragma unroll
        for (int i = 0; i < TILE; ++i) {
            float4 rw = tile[i][j];                          // LDS broadcast
            float t = __builtin_amdgcn_fractf(rw.x * kf);
            float c = trig ? __builtin_amdgcn_sinf(t)
                           : __builtin_amdgcn_cosf(t);
            accI[i] = fmaf(c, rw.y, accI[i]);
            accJ    = fmaf(c, rw.z, accJ);
        }
        if (!diag) {                                         // J-side scatter
            int row = tb*TILE + j;
            atomicAdd(&acc[row*DMODEL + feat], __float2int_rn(accJ * SCALE_F));
        }
    }
    #pragma unroll
    for (int i = 0; i < TILE; ++i) {                         // I-side scatter
        int row = ta*TILE + i;
        atomicAdd(&acc[row*DMODEL + feat], __float2int_rn(accI[i] * SCALE_F));
    }
}

// Convert fixed-point -> float and fused LayerNorm, in place (acc == out buffer).
__global__ __launch_bounds__(256) void ln_kernel(
    const int* __restrict__ acc,
    const float* __restrict__ gamma,
    const float* __restrict__ beta,
    const unsigned char* __restrict__ mask,
    float* __restrict__ out)
{
    const int i   = blockIdx.x;
    const int tid = threadIdx.x;

    float x = (float)acc[i*DMODEL + tid] * INV_SCALE_F;
    if (mask[i]) x = 0.0f;   // padded target row -> wf = 0 -> LN yields beta

    __shared__ float red[4];
    const int lane = tid & 63;
    const int wave = tid >> 6;

    float s = x;
    #pragma unroll
    for (int off = 32; off > 0; off >>= 1) s += __shfl_down(s, off);
    if (lane == 0) red[wave] = s;
    __syncthreads();
    const float mu = (red[0] + red[1] + red[2] + red[3]) * (1.0f / DMODEL);
    __syncthreads();

    const float d = x - mu;
    float s2 = d * d;
    #pragma unroll
    for (int off = 32; off > 0; off >>= 1) s2 += __shfl_down(s2, off);
    if (lane == 0) red[wave] = s2;
    __syncthreads();
    const float var  = (red[0] + red[1] + red[2] + red[3]) * (1.0f / DMODEL);
    const float rstd = rsqrtf(var + LN_EPS_F);

    out[i*DMODEL + tid] = d * rstd * gamma[tid] + beta[tid];
}

extern "C" void kernel_launch(void* const* d_in, const int* in_sizes, int n_in,
                              void* d_out, int out_size, void* d_ws, size_t ws_size,
                              hipStream_t stream) {
    const float* coords      = (const float*)d_in[0];
    const float* wavenumbers = (const float*)d_in[1];
    const float* gamma1      = (const float*)d_in[2];
    const float* beta1       = (const float*)d_in[3];
    const unsigned char* kpm = (const unsigned char*)d_in[4];
    float* out = (float*)d_out;
    int*   acc = (int*)d_out;   // reuse output buffer as fixed-point accumulator

    hipMemsetAsync(acc, 0, NTOK*DMODEL*sizeof(int), stream);
    wf_pair_kernel<<<NPAIRS, 256, 0, stream>>>(coords, wavenumbers, kpm, acc);
    ln_kernel<<<NTOK, 256, 0, stream>>>(acc, gamma1, beta1, kpm, out);
}

// Round 4
// 41.859 us; speedup vs baseline: 1.7445x; 1.7445x over previous
//
#include <hip/hip_runtime.h>
#include <hip/hip_bf16.h>
#include <math.h>

#define NTOK   1024
#define DMODEL 256
#define NFREQ  128
#define TBL    2048
#define FOUR_PI_F 12.566370614359172f
#define INV_2PI_F 0.15915494309189535f
#define EPS_F  1e-6f
#define LN_EPS_F 1e-5f

// One block per target i. Trig via LDS lookup table (cos,sin) of the full
// period (2048 entries, nearest-entry: phase err <= pi/2048 -> out err ~1e-2
// vs threshold 0.107). Thread tid: frequency f = tid&127, j-half = tid>>7.
// One ds_read_b64 per (j,f) yields BOTH cos and sin -> both output features.
// This removes all v_sin/v_cos from the inner loop (trans pipe was the wall:
// ~16cy/wave-instr fit from R1/R2). Fused LayerNorm at the end.
__global__ __launch_bounds__(256) void wf_ln_kernel(
    const float* __restrict__ coords,       // [N,3]
    const float* __restrict__ wavenumbers,  // [NFREQ]
    const float* __restrict__ gamma,        // [DMODEL]
    const float* __restrict__ beta,         // [DMODEL]
    const unsigned char* __restrict__ mask, // [N], nonzero = padded
    float* __restrict__ out)                // [N, DMODEL]
{
    const int i   = blockIdx.x;
    const int tid = threadIdx.x;

    __shared__ float2 tbl[TBL];      // (cos, sin)(2*pi*m/TBL)
    __shared__ float2 sh_rw[NTOK];   // (r/2pi, w)
    __shared__ float2 comb[NFREQ][2];
    __shared__ float  red[4];

    // Fill trig table (8 entries/thread) — the only trans-pipe use.
    for (int m = tid; m < TBL; m += 256) {
        float rev = (float)m * (1.0f / TBL);
        tbl[m] = make_float2(__builtin_amdgcn_cosf(rev), __builtin_amdgcn_sinf(rev));
    }

    const float tx = coords[i*3+0];
    const float ty = coords[i*3+1];
    const float tz = coords[i*3+2];

    for (int j = tid; j < NTOK; j += 256) {
        float dx = coords[j*3+0] - tx;
        float dy = coords[j*3+1] - ty;
        float dz = coords[j*3+2] - tz;
        float r  = sqrtf(dx*dx + dy*dy + dz*dz);
        bool valid = (mask[j] == 0) && (r > EPS_F);
        float w  = valid ? (1.0f / (FOUR_PI_F * r)) : 0.0f;
        sh_rw[j] = make_float2(r * INV_2PI_F, w);
    }
    __syncthreads();

    const int f    = tid & (NFREQ - 1);
    const int half = tid >> 7;
    const float kT = wavenumbers[f] * (float)TBL;  // (r/2pi)*kT = phase in table units
    const int j0   = half * (NTOK / 2);

    float ca = 0.0f, sa = 0.0f, cb = 0.0f, sb = 0.0f;  // 2 indep acc pairs
    #pragma unroll 8
    for (int j = j0; j < j0 + NTOK/2; j += 2) {
        float2 rw0 = sh_rw[j];
        float2 rw1 = sh_rw[j+1];
        int idx0 = ((int)fmaf(rw0.x, kT, 0.5f)) & (TBL - 1);
        int idx1 = ((int)fmaf(rw1.x, kT, 0.5f)) & (TBL - 1);
        float2 cs0 = tbl[idx0];
        float2 cs1 = tbl[idx1];
        ca = fmaf(cs0.x, rw0.y, ca);
        sa = fmaf(cs0.y, rw0.y, sa);
        cb = fmaf(cs1.x, rw1.y, cb);
        sb = fmaf(cs1.y, rw1.y, sb);
    }
    comb[f][half] = make_float2(ca + cb, sa + sb);
    __syncthreads();

    // out feature tid: tid<128 -> cos(real) of freq tid; tid>=128 -> sin(imag).
    float acc = (tid < NFREQ) ? (comb[f][0].x + comb[f][1].x)
                              : (comb[f][0].y + comb[f][1].y);

    // Target padded -> wf row zeroed before LN (LN then yields beta).
    if (mask[i] != 0) acc = 0.0f;

    // ---- fused LayerNorm over the 256 per-thread values (two-pass) ----
    const int lane = tid & 63;
    const int wave = tid >> 6;

    float s = acc;
    #pragma unroll
    for (int off = 32; off > 0; off >>= 1) s += __shfl_down(s, off);
    if (lane == 0) red[wave] = s;
    __syncthreads();
    const float mu = (red[0] + red[1] + red[2] + red[3]) * (1.0f / DMODEL);
    __syncthreads();

    const float d = acc - mu;
    float s2 = d * d;
    #pragma unroll
    for (int off = 32; off > 0; off >>= 1) s2 += __shfl_down(s2, off);
    if (lane == 0) red[wave] = s2;
    __syncthreads();
    const float var  = (red[0] + red[1] + red[2] + red[3]) * (1.0f / DMODEL);
    const float rstd = rsqrtf(var + LN_EPS_F);

    out[i*DMODEL + tid] = d * rstd * gamma[tid] + beta[tid];
}

extern "C" void kernel_launch(void* const* d_in, const int* in_sizes, int n_in,
                              void* d_out, int out_size, void* d_ws, size_t ws_size,
                              hipStream_t stream) {
    const float* coords      = (const float*)d_in[0];
    const float* wavenumbers = (const float*)d_in[1];
    const float* gamma1      = (const float*)d_in[2];
    const float* beta1       = (const float*)d_in[3];
    const unsigned char* kpm = (const unsigned char*)d_in[4];
    float* out = (float*)d_out;

    wf_ln_kernel<<<NTOK, 256, 0, stream>>>(coords, wavenumbers, gamma1, beta1, kpm, out);
}